// Round 14
// baseline (291.655 us; speedup 1.0000x reference)
//
#include <hip/hip_runtime.h>

// NeRF volume renderer, fp32 — R12: software-pipelined multi-ray waves.
// Inputs (setup_inputs order):
//   0 rays_o  [N,3]   1 rays_d [N,3]   2 sigmas [N,S]   3 rgbs [N,S,3]
//   4 sun_v   [N,S]   5 sky    [N,S,3] 6 nears  [N]     7 fars [N]
//   8 density_grid [G,G,G]
// Output: image [N,3] ++ depth [N] ++ weights_sum [N]  (flat f32)
//
// History: R6 (nt, 1 ray/wave) 98.6us @3.1TB/s; R7 (nt, float4) 111us
// @3.2TB/s; R11 (no-nt A/B) 114.9us @2.7TB/s -> nt helps, keep it.
// All three pin at ~5 B/cyc/CU with ideal FETCH: waves burst 10 loads,
// then idle the memory pipe for ~1000+cyc of scan/exp/reduce (cohort-
// synchronized) -> only ~75 lines in flight/CU vs ~145 needed for peak.
// R12: each wave streams RPW=8 rays with named A/B double buffers,
// issuing ray r+1's loads before computing ray r -> sustained issue.

#define NRAYS  65536
#define NSTEPS 128
#define GRIDN  128
#define RPW    8      // rays per wave
#define WPB    4      // waves per 256-thread block

typedef float v2f __attribute__((ext_vector_type(2)));

__device__ __forceinline__ v2f ntload2(const float* p) {
    return __builtin_nontemporal_load((const v2f*)p);
}

// Issue all memory for ray `rayi` into buffer P: scalar ray params, the
// lane's two grid gathers, then the 8 nt stream loads. Addresses use the
// same __fadd_rn/__fmul_rn (no-fma) discipline as COMPUTE so the grid
// index / inside test stay bit-identical to the XLA reference path.
#define PREFETCH(rayi, P)                                                      \
  do {                                                                         \
    const int _ray = (rayi);                                                   \
    P##_near = nears[_ray];  P##_far = fars[_ray];                             \
    P##_ox = rays_o[_ray*3+0]; P##_oy = rays_o[_ray*3+1]; P##_oz = rays_o[_ray*3+2]; \
    P##_dx = rays_d[_ray*3+0]; P##_dy = rays_d[_ray*3+1]; P##_dz = rays_d[_ray*3+2]; \
    const float _dt = (P##_far - P##_near) * (1.0f/NSTEPS);                    \
    _Pragma("unroll")                                                          \
    for (int _j = 0; _j < 2; ++_j) {                                           \
      const float _t = __fadd_rn(P##_near, __fmul_rn((float)(s0+_j)+0.5f, _dt)); \
      const float _x = __fadd_rn(P##_ox, __fmul_rn(_t, P##_dx));               \
      const float _y = __fadd_rn(P##_oy, __fmul_rn(_t, P##_dy));               \
      const float _z = __fadd_rn(P##_oz, __fmul_rn(_t, P##_dz));               \
      int _ix = (int)__fmul_rn(__fadd_rn(_x, 1.0f), 64.0f);                    \
      int _iy = (int)__fmul_rn(__fadd_rn(_y, 1.0f), 64.0f);                    \
      int _iz = (int)__fmul_rn(__fadd_rn(_z, 1.0f), 64.0f);                    \
      _ix = min(max(_ix,0),GRIDN-1); _iy = min(max(_iy,0),GRIDN-1); _iz = min(max(_iz,0),GRIDN-1); \
      const float _g = grid[((long)_ix*GRIDN + _iy)*GRIDN + _iz];              \
      if (_j == 0) P##_g0 = _g; else P##_g1 = _g;                              \
    }                                                                          \
    const long _base = (long)_ray * NSTEPS + s0;                               \
    P##_sg  = ntload2(sigmas + _base);                                         \
    P##_sv  = ntload2(sun_v  + _base);                                         \
    P##_r01 = ntload2(rgbs + _base*3);                                         \
    P##_r23 = ntload2(rgbs + _base*3 + 2);                                     \
    P##_r45 = ntload2(rgbs + _base*3 + 4);                                     \
    P##_k01 = ntload2(sky  + _base*3);                                         \
    P##_k23 = ntload2(sky  + _base*3 + 2);                                     \
    P##_k45 = ntload2(sky  + _base*3 + 4);                                     \
  } while (0)

// Consume buffer P for ray `rayi`: verbatim R6 per-ray math (shading,
// one 64-lane exclusive scan, compositing, 5-way butterfly reduce, store).
#define COMPUTE(rayi, P)                                                       \
  do {                                                                         \
    const int _ray = (rayi);                                                   \
    const float _dt = (P##_far - P##_near) * (1.0f/NSTEPS);                    \
    float t_[2], tau_[2], cr_[2], cg_[2], cb_[2];                              \
    const float rr_[2] = { P##_r01[0], P##_r23[1] };                           \
    const float rg_[2] = { P##_r01[1], P##_r45[0] };                           \
    const float rb_[2] = { P##_r23[0], P##_r45[1] };                           \
    const float kr_[2] = { P##_k01[0], P##_k23[1] };                           \
    const float kg_[2] = { P##_k01[1], P##_k45[0] };                           \
    const float kb_[2] = { P##_k23[0], P##_k45[1] };                           \
    const float g_[2]  = { P##_g0, P##_g1 };                                   \
    _Pragma("unroll")                                                          \
    for (int _j = 0; _j < 2; ++_j) {                                           \
      const float _t = __fadd_rn(P##_near, __fmul_rn((float)(s0+_j)+0.5f, _dt)); \
      const float _x = __fadd_rn(P##_ox, __fmul_rn(_t, P##_dx));               \
      const float _y = __fadd_rn(P##_oy, __fmul_rn(_t, P##_dy));               \
      const float _z = __fadd_rn(P##_oz, __fmul_rn(_t, P##_dz));               \
      const bool _inside = (fabsf(_x) < 1.0f) & (fabsf(_y) < 1.0f) & (fabsf(_z) < 1.0f); \
      const bool _occ    = (g_[_j] > 0.01f) & _inside;                         \
      const float _sig = _occ ? P##_sg[_j] : 0.0f;                             \
      const float _sv  = P##_sv[_j];                                           \
      cr_[_j] = rr_[_j] * (_sv + (1.0f - _sv) * kr_[_j]);                      \
      cg_[_j] = rg_[_j] * (_sv + (1.0f - _sv) * kg_[_j]);                      \
      cb_[_j] = rb_[_j] * (_sv + (1.0f - _sv) * kb_[_j]);                      \
      t_[_j]   = _t;                                                           \
      tau_[_j] = _sig * _dt;                                                   \
    }                                                                          \
    const float _pair = tau_[0] + tau_[1];                                     \
    float _incl = _pair;                                                       \
    _Pragma("unroll")                                                          \
    for (int _off = 1; _off < 64; _off <<= 1) {                                \
      const float _u = __shfl_up(_incl, _off);                                 \
      if (lane >= _off) _incl += _u;                                           \
    }                                                                          \
    const float _eLane = _incl - _pair;                                        \
    const float excl_[2] = { _eLane, _eLane + tau_[0] };                       \
    float _ws = 0.0f, _ds = 0.0f, _ir = 0.0f, _ig = 0.0f, _ib = 0.0f;          \
    _Pragma("unroll")                                                          \
    for (int _j = 0; _j < 2; ++_j) {                                           \
      const float _T     = expf(-excl_[_j]);                                   \
      const float _alpha = 1.0f - expf(-tau_[_j]);                             \
      const float _w     = (_T > 1e-3f) ? _alpha * _T : 0.0f;                  \
      _ws += _w; _ds += _w * t_[_j];                                           \
      _ir += _w * cr_[_j]; _ig += _w * cg_[_j]; _ib += _w * cb_[_j];           \
    }                                                                          \
    _Pragma("unroll")                                                          \
    for (int _off = 32; _off > 0; _off >>= 1) {                                \
      _ws += __shfl_xor(_ws, _off);                                            \
      _ds += __shfl_xor(_ds, _off);                                            \
      _ir += __shfl_xor(_ir, _off);                                            \
      _ig += __shfl_xor(_ig, _off);                                            \
      _ib += __shfl_xor(_ib, _off);                                            \
    }                                                                          \
    if (lane == 0) {                                                           \
      const float _bgw = 1.0f - _ws;                                           \
      out[_ray*3 + 0] = _ir + _bgw;                                            \
      out[_ray*3 + 1] = _ig + _bgw;                                            \
      out[_ray*3 + 2] = _ib + _bgw;                                            \
      out[3*NRAYS + _ray] = fmaxf(_ds - P##_near, 0.0f) / (P##_far - P##_near);\
      out[4*NRAYS + _ray] = _ws;                                               \
    }                                                                          \
  } while (0)

__global__ __launch_bounds__(256, 4) void nerf_render_kernel(
    const float* __restrict__ rays_o,
    const float* __restrict__ rays_d,
    const float* __restrict__ sigmas,
    const float* __restrict__ rgbs,
    const float* __restrict__ sun_v,
    const float* __restrict__ sky,
    const float* __restrict__ nears,
    const float* __restrict__ fars,
    const float* __restrict__ grid,
    float* __restrict__ out)
{
    const int lane = threadIdx.x & 63;
    // readfirstlane: guarantee wave-uniform ray index -> scalar param loads
    const int wloc = __builtin_amdgcn_readfirstlane(threadIdx.x >> 6);
    const int wave = blockIdx.x * WPB + wloc;
    const int ray0 = wave * RPW;
    const int s0   = 2 * lane;          // lane's first sample (pair layout)

    // named double buffers (no runtime-indexed arrays -> no scratch)
    v2f A_sg, A_sv, A_r01, A_r23, A_r45, A_k01, A_k23, A_k45;
    float A_g0, A_g1, A_near, A_far, A_ox, A_oy, A_oz, A_dx, A_dy, A_dz;
    v2f B_sg, B_sv, B_r01, B_r23, B_r45, B_k01, B_k23, B_k45;
    float B_g0, B_g1, B_near, B_far, B_ox, B_oy, B_oz, B_dx, B_dy, B_dz;

    PREFETCH(ray0 + 0, A);
    PREFETCH(ray0 + 1, B);  COMPUTE(ray0 + 0, A);
    PREFETCH(ray0 + 2, A);  COMPUTE(ray0 + 1, B);
    PREFETCH(ray0 + 3, B);  COMPUTE(ray0 + 2, A);
    PREFETCH(ray0 + 4, A);  COMPUTE(ray0 + 3, B);
    PREFETCH(ray0 + 5, B);  COMPUTE(ray0 + 4, A);
    PREFETCH(ray0 + 6, A);  COMPUTE(ray0 + 5, B);
    PREFETCH(ray0 + 7, B);  COMPUTE(ray0 + 6, A);
                            COMPUTE(ray0 + 7, B);
}

extern "C" void kernel_launch(void* const* d_in, const int* in_sizes, int n_in,
                              void* d_out, int out_size, void* d_ws, size_t ws_size,
                              hipStream_t stream) {
    const float* rays_o = (const float*)d_in[0];
    const float* rays_d = (const float*)d_in[1];
    const float* sigmas = (const float*)d_in[2];
    const float* rgbs   = (const float*)d_in[3];
    const float* sun_v  = (const float*)d_in[4];
    const float* sky    = (const float*)d_in[5];
    const float* nears  = (const float*)d_in[6];
    const float* fars   = (const float*)d_in[7];
    const float* grid   = (const float*)d_in[8];
    float* out = (float*)d_out;

    const int threads = 256;                         // 4 waves/block
    const int blocks  = NRAYS / (WPB * RPW);         // 2048 blocks
    nerf_render_kernel<<<blocks, threads, 0, stream>>>(
        rays_o, rays_d, sigmas, rgbs, sun_v, sky, nears, fars, grid, out);
}